// Round 11
// baseline (2829.293 us; speedup 1.0000x reference)
//
#include <hip/hip_runtime.h>
#include <math.h>

#define BB 4
#define SS 512
#define SE 512
#define DD 1024
#define HH 16
#define FFD 4096
#define NHOP 6

typedef float f32x4 __attribute__((ext_vector_type(4)));
typedef _Float16 h8 __attribute__((ext_vector_type(8)));
typedef _Float16 h4 __attribute__((ext_vector_type(4)));

#define GLD16(gp, lp)                                                     \
  __builtin_amdgcn_global_load_lds(                                       \
      (const __attribute__((address_space(1))) void*)(gp),                \
      (__attribute__((address_space(3))) void*)(lp), 16, 0, 0)

template <int N>
__device__ __forceinline__ void vwait() {
  if constexpr (N == 0) asm volatile("s_waitcnt vmcnt(0)" ::: "memory");
  else if constexpr (N == 6) asm volatile("s_waitcnt vmcnt(6)" ::: "memory");
  else if constexpr (N == 8) asm volatile("s_waitcnt vmcnt(8)" ::: "memory");
  else if constexpr (N == 12) asm volatile("s_waitcnt vmcnt(12)" ::: "memory");
}

// ---------------- block reduction (256 threads = 4 waves) ----------------
__device__ __forceinline__ float blockSum256(float v, float* s4) {
#pragma unroll
  for (int m = 32; m >= 1; m >>= 1) v += __shfl_xor(v, m);
  __syncthreads();
  if ((threadIdx.x & 63) == 0) s4[threadIdx.x >> 6] = v;
  __syncthreads();
  return s4[0] + s4[1] + s4[2] + s4[3];
}

__device__ __forceinline__ void split16(float v, _Float16& h, _Float16& l) {
  h = (_Float16)v;
  l = (_Float16)(v - (float)h);
}

// swizzled LDS element offset for [64 rows][8 slots of 8 fp16] (BK=64 tiles)
__device__ __forceinline__ int swzel(int row, int slot) {
  return (row << 6) + ((slot ^ (row & 7)) << 3);
}

// ---------------- sincos position/time codes (fp64, matches numpy) -------
__global__ void sincos_kernel(float* __restrict__ out, int n) {
  for (int i = blockIdx.x * blockDim.x + threadIdx.x; i < n;
       i += gridDim.x * blockDim.x) {
    int p = i >> 10, d = i & 1023, j = d >> 1;
    double ang = (double)p / pow(10000.0, (2.0 * j) / 1024.0);
    out[i] = (float)((d & 1) ? cos(ang) : sin(ang));
  }
}

// ---------------- embedding gather * sqrt(D) ------------------------------
__global__ void embed_kernel(const int* __restrict__ tok,
                             const float* __restrict__ emb,
                             float* __restrict__ out, int n) {
  for (int i = blockIdx.x * blockDim.x + threadIdx.x; i < n;
       i += gridDim.x * blockDim.x) {
    int row = i >> 10, d = i & 1023;
    out[i] = emb[(size_t)tok[row] * DD + d] * 32.0f;
  }
}

// ---------------- fp32 -> hi/lo fp16 planes (same layout) ----------------
__global__ void asplit_kernel(const float* __restrict__ x,
                              _Float16* __restrict__ h,
                              _Float16* __restrict__ l, int n) {
  for (int i = blockIdx.x * blockDim.x + threadIdx.x; i < n;
       i += gridDim.x * blockDim.x)
    split16(x[i], h[i], l[i]);
}

// ---------------- fused: tensor+codes -> TIN planes AND ACT halting ------
__global__ __launch_bounds__(256)
void actcodes_kernel(const float* __restrict__ ten, const float* __restrict__ pos,
                     const float* __restrict__ tim, int hop,
                     const float* __restrict__ aw, const float* __restrict__ ab,
                     float* __restrict__ hp, float* __restrict__ rem,
                     float* __restrict__ uw, _Float16* __restrict__ th,
                     _Float16* __restrict__ tl) {
  __shared__ float s4[4];
  int row = blockIdx.x;
  int srow = row & 511;
  size_t base = (size_t)row * DD;
  float s = 0.f;
#pragma unroll
  for (int k = 0; k < 4; ++k) {
    int d = threadIdx.x + k * 256;
    float v = ten[base + d] + pos[(srow << 10) + d] + tim[(hop << 10) + d];
    split16(v, th[base + d], tl[base + d]);
    s += v * aw[d];
  }
  float z = blockSum256(s, s4);
  if (threadIdx.x == 0) {
    z += ab[0];
    float p = 1.0f / (1.0f + expf(-z));
    float h = hp[row], rm = rem[row];
    float s0 = (h < 1.0f) ? 1.0f : 0.0f;
    float cond = h + p * s0;
    float nh = (cond > 0.99f) ? s0 : 0.0f;
    float s1 = (cond <= 0.99f) ? s0 : 0.0f;
    h = h + p * s1;
    rm = rm + nh * (1.0f - h);
    h = h + nh * rm;
    hp[row] = h;
    rem[row] = rm;
    uw[row] = p * s1 + nh * rm;
  }
}

// ---------------- fused residual + LayerNorm (+ optional prev update) ----
__global__ __launch_bounds__(256)
void lnres_kernel(const float* __restrict__ a, const _Float16* __restrict__ rh,
                  const _Float16* __restrict__ rl, const float* __restrict__ g,
                  const float* __restrict__ be, float* __restrict__ outf,
                  _Float16* __restrict__ oh, _Float16* __restrict__ ol,
                  const float* __restrict__ uwv, float* __restrict__ po,
                  int mode) {
  __shared__ float s4[4];
  int row = blockIdx.x;
  size_t base = (size_t)row * DD;
  float x[4];
#pragma unroll
  for (int k = 0; k < 4; ++k) {
    size_t idx = base + threadIdx.x + k * 256;
    x[k] = a[idx] + ((float)rh[idx] + (float)rl[idx]);
  }
  float mean = blockSum256(x[0] + x[1] + x[2] + x[3], s4) * (1.0f / 1024.0f);
  float q = 0.f;
#pragma unroll
  for (int k = 0; k < 4; ++k) {
    float dv = x[k] - mean;
    q += dv * dv;
  }
  float var = blockSum256(q, s4) * (1.0f / 1024.0f);
  float inv = 1.0f / sqrtf(var + 1e-12f);
  float u = (mode == 0) ? uwv[row] : 0.f;
#pragma unroll
  for (int k = 0; k < 4; ++k) {
    int d = threadIdx.x + k * 256;
    size_t idx = base + d;
    float y = (x[k] - mean) * inv * g[d] + be[d];
    if (mode == 0) {
      outf[idx] = y;
      po[idx] = y * u + po[idx] * (1.0f - u);  // prev update fused
    } else {
      split16(y, oh[idx], ol[idx]);
    }
  }
}

// ---------------- weight transpose + fp16 hi/lo split --------------------
__global__ __launch_bounds__(256)
void wsplit_kernel(const float* __restrict__ W, _Float16* __restrict__ WhT,
                   _Float16* __restrict__ WlT, int K, int N) {
  __shared__ float t[32][33];
  int k0 = blockIdx.y << 5, n0 = blockIdx.x << 5;
  int c = threadIdx.x & 31, r8 = threadIdx.x >> 5;
  for (int rr = r8; rr < 32; rr += 8)
    t[rr][c] = W[(size_t)(k0 + rr) * N + n0 + c];
  __syncthreads();
  for (int rr = r8; rr < 32; rr += 8) {
    float v = t[c][rr];
    split16(v, WhT[(size_t)(n0 + rr) * K + k0 + c],
            WlT[(size_t)(n0 + rr) * K + k0 + c]);
  }
}

// ---------------- concat 3 bias vectors ----------------------------------
__global__ void concat3_kernel(const float* __restrict__ a,
                               const float* __restrict__ b,
                               const float* __restrict__ c,
                               float* __restrict__ o) {
  int i = blockIdx.x * 256 + threadIdx.x;
  if (i < 3072) o[i] = (i < 1024) ? a[i] : ((i < 2048) ? b[i - 1024] : c[i - 2048]);
}

// ---------------- DD-size split-fp16 MFMA GEMM (64x64, BK=64) ------------
// A via LDS (gload_lds dbuf, swizzled); B via global->register ping-pong
// prefetch (halves LDS traffic -> MFMA-bound; 3 blocks/CU).
// EPI 0: fp32 out. EPI 1: relu -> planes. EPI 3: head-blocked planes*scale.
// EPI 4: V transposed planes only.
template <int EPI>
__global__ __launch_bounds__(256) void gemm_pl(
    const _Float16* __restrict__ Ah, const _Float16* __restrict__ Al,
    const _Float16* __restrict__ Bh, const _Float16* __restrict__ Bl,
    const float* __restrict__ bias, float* __restrict__ Cf,
    _Float16* __restrict__ Ch, _Float16* __restrict__ Cl,
    _Float16* __restrict__ Ch2, _Float16* __restrict__ Cl2,
    _Float16* __restrict__ Ch3, _Float16* __restrict__ Cl3, int M, int N,
    int K, float scale) {
  __shared__ __align__(16) _Float16 sA0[2][4096], sA1[2][4096];
  const int tid = threadIdx.x;
  const int lane = tid & 63, wid = tid >> 6;
  const int wr = wid >> 1, wc = wid & 1;
  int bx = blockIdx.x, by = blockIdx.y;
  {
    int nb = gridDim.x * gridDim.y;
    if ((nb & 7) == 0) {
      int flat = by * gridDim.x + bx;
      int swz = (flat & 7) * (nb >> 3) + (flat >> 3);
      bx = swz % gridDim.x;
      by = swz / gridDim.x;
    }
  }
  const int m0 = by << 6, n0 = bx << 6;
  const int l15 = lane & 15, l4 = lane >> 4;

  f32x4 acc[2][2];
#pragma unroll
  for (int i = 0; i < 2; ++i)
#pragma unroll
    for (int j = 0; j < 2; ++j) acc[i][j] = (f32x4){0.f, 0.f, 0.f, 0.f};

  // A staging: 2 chunks/thread/plane; LDS[r][s'] = G[r][s' ^ (r&7)]
  auto STAGE = [&](int kt, int buf) {
    const int ko = kt << 6;
#pragma unroll
    for (int c = 0; c < 2; ++c) {
      int idx = (c << 8) + tid;
      int row = idx >> 3, gs = (idx & 7) ^ (row & 7);
      int de = (c << 11) + (wid << 9);
      size_t ga = (size_t)(m0 + row) * K + ko + (gs << 3);
      GLD16(Ah + ga, &sA0[buf][de]);
      GLD16(Al + ga, &sA1[buf][de]);
    }
  };
  // B fragment loads: global -> regs (L2-hot weight panel)
  auto BLOAD = [&](int kt, h8 (&c0)[2][2], h8 (&c1)[2][2]) {
#pragma unroll
    for (int f = 0; f < 2; ++f)
#pragma unroll
      for (int ks = 0; ks < 2; ++ks) {
        int n = (wc << 5) + (f << 4) + l15;
        size_t gb = (size_t)(n0 + n) * K + (kt << 6) + (ks << 5) + (l4 << 3);
        c0[f][ks] = *(const h8*)(Bh + gb);
        c1[f][ks] = *(const h8*)(Bl + gb);
      }
  };
  auto COMPUTE = [&](int buf, h8 (&c0)[2][2], h8 (&c1)[2][2]) {
    const _Float16* pA0 = sA0[buf];
    const _Float16* pA1 = sA1[buf];
#pragma unroll
    for (int ks = 0; ks < 2; ++ks) {
      h8 a0[2], a1[2];
#pragma unroll
      for (int f = 0; f < 2; ++f) {
        int m = (wr << 5) + (f << 4) + l15;
        int so = swzel(m, (ks << 2) + l4);
        a0[f] = *(const h8*)&pA0[so];
        a1[f] = *(const h8*)&pA1[so];
      }
#pragma unroll
      for (int fi = 0; fi < 2; ++fi)
#pragma unroll
        for (int fj = 0; fj < 2; ++fj) {
          acc[fi][fj] = __builtin_amdgcn_mfma_f32_16x16x32_f16(
              a0[fi], c0[fj][ks], acc[fi][fj], 0, 0, 0);
          acc[fi][fj] = __builtin_amdgcn_mfma_f32_16x16x32_f16(
              a1[fi], c0[fj][ks], acc[fi][fj], 0, 0, 0);
          acc[fi][fj] = __builtin_amdgcn_mfma_f32_16x16x32_f16(
              a0[fi], c1[fj][ks], acc[fi][fj], 0, 0, 0);
        }
    }
  };

  h8 e0[2][2], e1[2][2], o0[2][2], o1[2][2];
  const int nk = K >> 6;  // 16 or 64 -> always even
  STAGE(0, 0);
  BLOAD(0, e0, e1);
  int cur = 0;
  for (int kt = 0; kt + 1 < nk; kt += 2) {
    // even step kt: consume (e), prefetch kt+1 into (o)
    STAGE(kt + 1, cur ^ 1);
    BLOAD(kt + 1, o0, o1);
    vwait<12>();  // A(kt) landed; A(kt+1)+B(kt+1)=12 stay in flight
    __builtin_amdgcn_s_barrier();
    __builtin_amdgcn_sched_barrier(0);
    COMPUTE(cur, e0, e1);
    __builtin_amdgcn_sched_barrier(0);
    __builtin_amdgcn_s_barrier();
    cur ^= 1;
    // odd step kt+1: consume (o), prefetch kt+2 into (e)
    if (kt + 2 < nk) {
      STAGE(kt + 2, cur ^ 1);
      BLOAD(kt + 2, e0, e1);
      vwait<12>();
    } else {
      vwait<0>();
    }
    __builtin_amdgcn_s_barrier();
    __builtin_amdgcn_sched_barrier(0);
    COMPUTE(cur, o0, o1);
    __builtin_amdgcn_sched_barrier(0);
    __builtin_amdgcn_s_barrier();
    cur ^= 1;
  }
  // epilogue: C/D layout col=lane&15, row=(lane>>4)*4+r
#pragma unroll
  for (int fi = 0; fi < 2; ++fi) {
    int row = m0 + (wr << 5) + (fi << 4) + (l4 << 2);
#pragma unroll
    for (int fj = 0; fj < 2; ++fj) {
      int col = n0 + (wc << 5) + (fj << 4) + l15;
      float bz = bias[col];
      float ov[4];
#pragma unroll
      for (int r = 0; r < 4; ++r) ov[r] = acc[fi][fj][r] + bz;
      if (EPI == 0) {
#pragma unroll
        for (int r = 0; r < 4; ++r) Cf[(size_t)(row + r) * N + col] = ov[r];
      } else if (EPI == 1) {
#pragma unroll
        for (int r = 0; r < 4; ++r) {
          float o = fmaxf(ov[r], 0.f);
          size_t idx = (size_t)(row + r) * N + col;
          split16(o, Ch[idx], Cl[idx]);
        }
      } else if (EPI == 3) {
        int b = row >> 9, h = col >> 6, d = col & 63;
#pragma unroll
        for (int r = 0; r < 4; ++r) {
          int sr = (row + r) & 511;
          size_t q = ((size_t)(b * HH + h) * SS + sr) * 64 + d;
          split16(ov[r] * scale, Ch[q], Cl[q]);
        }
      } else if (EPI == 4) {  // V transposed planes: Vt[bh][d][s]
        int b = row >> 9, s0 = row & 511, h = col >> 6, d = col & 63;
        h4 hv, lv;
#pragma unroll
        for (int r = 0; r < 4; ++r) {
          _Float16 hh, ll;
          split16(ov[r], hh, ll);
          hv[r] = hh;
          lv[r] = ll;
        }
        size_t vo = ((size_t)(b * HH + h) * 64 + d) * SS + s0;
        *(h4*)&Ch[vo] = hv;
        *(h4*)&Cl[vo] = lv;
      }
    }
  }
}

// ---------------- big-N split-fp16 MFMA GEMM (128x64 tile, BK=32) --------
// R7-proven staging/swizzle. EPI 1: relu -> planes. EPI 2: QKV dispatch
// (Q/K head planes + Vt planes).
template <int EPI>
__global__ __launch_bounds__(256) void gemm_big(
    const _Float16* __restrict__ Ah, const _Float16* __restrict__ Al,
    const _Float16* __restrict__ Bh, const _Float16* __restrict__ Bl,
    const float* __restrict__ bias, _Float16* __restrict__ Ch,
    _Float16* __restrict__ Cl, _Float16* __restrict__ Ch2,
    _Float16* __restrict__ Cl2, _Float16* __restrict__ Ch3,
    _Float16* __restrict__ Cl3, int M, int N, int K, float scale) {
  constexpr int FM = 4, FN = 2;
  constexpr int MT = 128, NT = 64;
  constexpr int SA = 2, SB = 1;   // 16B chunks/thread/plane
  constexpr int L = 2 * (SA + SB);
  __shared__ __align__(16) _Float16 sA0[2][MT * 32], sA1[2][MT * 32];
  __shared__ __align__(16) _Float16 sB0[2][NT * 32], sB1[2][NT * 32];
  const int tid = threadIdx.x;
  const int lane = tid & 63, wid = tid >> 6;
  const int wr = wid >> 1, wc = wid & 1;
  int bx = blockIdx.x, by = blockIdx.y;
  {
    int nb = gridDim.x * gridDim.y;
    if ((nb & 7) == 0) {
      int flat = by * gridDim.x + bx;
      int swz = (flat & 7) * (nb >> 3) + (flat >> 3);
      bx = swz % gridDim.x;
      by = swz / gridDim.x;
    }
  }
  const int m0 = by * MT, n0 = bx * NT;
  const int l15 = lane & 15, l4 = lane >> 4;

  f32x4 acc[FM][FN];
#pragma unroll
  for (int i = 0; i < FM; ++i)
#pragma unroll
    for (int j = 0; j < FN; ++j) acc[i][j] = (f32x4){0.f, 0.f, 0.f, 0.f};

  auto STAGE = [&](int kt, int buf) {
    const int ko = kt << 5;
#pragma unroll
    for (int c = 0; c < SA; ++c) {
      int slot = tid + (c << 8);
      int row = slot >> 2, sl = slot & 3;
      int of = ((sl ^ ((row >> 1) & 3)) << 3);
      size_t ga = (size_t)(m0 + row) * K + ko + of;
      int de = (wid << 9) + (c << 11);
      GLD16(Ah + ga, &sA0[buf][de]);
      GLD16(Al + ga, &sA1[buf][de]);
    }
#pragma unroll
    for (int c = 0; c < SB; ++c) {
      int slot = tid + (c << 8);
      int row = slot >> 2, sl = slot & 3;
      int of = ((sl ^ ((row >> 1) & 3)) << 3);
      size_t gb = (size_t)(n0 + row) * K + ko + of;
      int de = (wid << 9) + (c << 11);
      GLD16(Bh + gb, &sB0[buf][de]);
      GLD16(Bl + gb, &sB1[buf][de]);
    }
  };

  const int nk = K >> 5;
  STAGE(0, 0);
  int cur = 0;
  for (int kt = 0; kt < nk; ++kt) {
    if (kt + 1 < nk) {
      STAGE(kt + 1, cur ^ 1);
      vwait<L>();
    } else {
      vwait<0>();
    }
    __builtin_amdgcn_s_barrier();
    __builtin_amdgcn_sched_barrier(0);
    const _Float16* pA0 = sA0[cur];
    const _Float16* pA1 = sA1[cur];
    const _Float16* pB0 = sB0[cur];
    const _Float16* pB1 = sB1[cur];
    h8 a0[FM], a1[FM], b0[FN], b1[FN];
#pragma unroll
    for (int f = 0; f < FM; ++f) {
      int m = wr * (FM * 16) + f * 16 + l15;
      int st = ((l4 ^ ((m >> 1) & 3)) << 3);
      a0[f] = *(const h8*)&pA0[(m << 5) + st];
      a1[f] = *(const h8*)&pA1[(m << 5) + st];
    }
#pragma unroll
    for (int f = 0; f < FN; ++f) {
      int n = wc * (FN * 16) + f * 16 + l15;
      int sn = ((l4 ^ ((n >> 1) & 3)) << 3);
      b0[f] = *(const h8*)&pB0[(n << 5) + sn];
      b1[f] = *(const h8*)&pB1[(n << 5) + sn];
    }
#pragma unroll
    for (int fi = 0; fi < FM; ++fi)
#pragma unroll
      for (int fj = 0; fj < FN; ++fj) {
        acc[fi][fj] = __builtin_amdgcn_mfma_f32_16x16x32_f16(
            a0[fi], b0[fj], acc[fi][fj], 0, 0, 0);
        acc[fi][fj] = __builtin_amdgcn_mfma_f32_16x16x32_f16(
            a1[fi], b0[fj], acc[fi][fj], 0, 0, 0);
        acc[fi][fj] = __builtin_amdgcn_mfma_f32_16x16x32_f16(
            a0[fi], b1[fj], acc[fi][fj], 0, 0, 0);
      }
    __builtin_amdgcn_sched_barrier(0);
    __builtin_amdgcn_s_barrier();
    cur ^= 1;
  }
#pragma unroll
  for (int fi = 0; fi < FM; ++fi) {
    int row = m0 + wr * (FM * 16) + fi * 16 + (l4 << 2);
#pragma unroll
    for (int fj = 0; fj < FN; ++fj) {
      int col = n0 + wc * (FN * 16) + fj * 16 + l15;
      float bz = bias[col];
      float ov[4];
#pragma unroll
      for (int r = 0; r < 4; ++r) ov[r] = acc[fi][fj][r] + bz;
      if (EPI == 1) {
#pragma unroll
        for (int r = 0; r < 4; ++r) {
          float o = fmaxf(ov[r], 0.f);
          size_t idx = (size_t)(row + r) * N + col;
          split16(o, Ch[idx], Cl[idx]);
        }
      } else {  // EPI == 2: QKV dispatch (Q planes, K planes, Vt planes)
        int reg = col >> 10;  // wave-uniform per block (NT=64 divides 1024)
        int c = col & 1023;
        int b = row >> 9, h = c >> 6, d = c & 63;
        if (reg == 2) {
          int s0 = row & 511;
          h4 hv, lv;
#pragma unroll
          for (int r = 0; r < 4; ++r) {
            _Float16 hh, ll;
            split16(ov[r], hh, ll);
            hv[r] = hh;
            lv[r] = ll;
          }
          size_t vo = ((size_t)(b * HH + h) * 64 + d) * SS + s0;
          *(h4*)&Ch3[vo] = hv;
          *(h4*)&Cl3[vo] = lv;
        } else {
#pragma unroll
          for (int r = 0; r < 4; ++r) {
            float o = (reg == 0) ? ov[r] * scale : ov[r];
            int sr = (row + r) & 511;
            size_t q = ((size_t)(b * HH + h) * SS + sr) * 64 + d;
            if (reg == 0) split16(o, Ch[q], Cl[q]);
            else split16(o, Ch2[q], Cl2[q]);
          }
        }
      }
    }
  }
}

// ---------------- MFMA flash attention (counted-vmcnt pipelined) ---------
template <int CAUSAL>
__global__ __launch_bounds__(256) void flash_mfma(
    const _Float16* __restrict__ Qph, const _Float16* __restrict__ Qpl,
    const _Float16* __restrict__ Kph, const _Float16* __restrict__ Kpl,
    const _Float16* __restrict__ Vph, const _Float16* __restrict__ Vpl,
    _Float16* __restrict__ AOh, _Float16* __restrict__ AOl,
    const int* __restrict__ mask, int Sk) {
  __shared__ __align__(16) _Float16 sKh[2][4096], sKl[2][4096];
  __shared__ __align__(16) _Float16 sVh[2][4096], sVl[2][4096];
  __shared__ __align__(16) _Float16 sPh[4096], sPl[4096];
  const int tid = threadIdx.x, lane = tid & 63, wid = tid >> 6;
  const int l15 = lane & 15, l4 = lane >> 4;
  const int flat = blockIdx.x;
  const int bh = flat >> 3, b = bh >> 4;
  int qt = flat & 7;
  if (CAUSAL && (flat >> 8)) qt = 7 - qt;
  const size_t qkb = (size_t)bh * SS * 64;
  const size_t vtb = (size_t)bh * 64 * Sk;

  int srow[2], slg[2], sde[2];
#pragma unroll
  for (int c = 0; c < 2; ++c) {
    int u = (c << 8) + tid;
    srow[c] = u >> 3;
    slg[c] = (u & 7) ^ (srow[c] & 7);
    sde[c] = (c << 11) + (wid << 9);
  }

  unsigned mbits = 0xFFFFFFFFu;
  if (!CAUSAL && mask != nullptr) {
    mbits = 0u;
#pragma unroll
    for (int kt = 0; kt < 8; ++kt)
#pragma unroll
      for (int fj = 0; fj < 4; ++fj)
        mbits |= (mask[b * Sk + kt * 64 + fj * 16 + l15] != 0 ? 1u : 0u)
                 << (kt * 4 + fj);
  }

  h8 aqh[2], aql[2];
#pragma unroll
  for (int ks = 0; ks < 2; ++ks) {
    size_t qa = qkb + (size_t)(qt * 64 + wid * 16 + l15) * 64 + ks * 32 + l4 * 8;
    aqh[ks] = *(const h8*)(Qph + qa);
    aql[ks] = *(const h8*)(Qpl + qa);
  }
  f32x4 o_[4];
  float m_[4], l_[4];
#pragma unroll
  for (int i = 0; i < 4; ++i) o_[i] = (f32x4){0.f, 0.f, 0.f, 0.f};
#pragma unroll
  for (int r = 0; r < 4; ++r) { m_[r] = -3.0e38f; l_[r] = 0.f; }

  auto STAGE = [&](int kt, int buf) {
#pragma unroll
    for (int c = 0; c < 2; ++c) {
      size_t ksrc = qkb + (size_t)(kt * 64 + srow[c]) * 64 + slg[c] * 8;
      size_t vsrc = vtb + (size_t)srow[c] * Sk + kt * 64 + slg[c] * 8;
      GLD16(Kph + ksrc, &sKh[buf][sde[c]]);
      GLD16(Kpl + ksrc, &sKl[buf][sde[c]]);
      GLD16(Vph + vsrc, &sVh[buf][sde[c]]);
      GLD16(Vpl + vsrc, &sVl[buf][sde[c]]);
    }
  };

  const int nkt = CAUSAL ? (qt + 1) : (Sk >> 6);
  STAGE(0, 0);
  int cur = 0;
  for (int kt = 0; kt < nkt; ++kt) {
    if (kt + 1 < nkt) {
      STAGE(kt + 1, cur ^ 1);
      vwait<8>();
    } else {
      vwait<0>();
    }
    __builtin_amdgcn_s_barrier();
    __builtin_amdgcn_sched_barrier(0);
    const _Float16* pKh = sKh[cur];
    const _Float16* pKl = sKl[cur];
    const _Float16* pVh = sVh[cur];
    const _Float16* pVl = sVl[cur];
    f32x4 sc[4];
#pragma unroll
    for (int fj = 0; fj < 4; ++fj) {
      sc[fj] = (f32x4){0.f, 0.f, 0.f, 0.f};
#pragma unroll
      for (int ks = 0; ks < 2; ++ks) {
        int off = swzel(fj * 16 + l15, ks * 4 + l4);
        h8 bkh = *(const h8*)&pKh[off];
        h8 bkl = *(const h8*)&pKl[off];
        sc[fj] = __builtin_amdgcn_mfma_f32_16x16x32_f16(aqh[ks], bkh, sc[fj], 0, 0, 0);
        sc[fj] = __builtin_amdgcn_mfma_f32_16x16x32_f16(aql[ks], bkh, sc[fj], 0, 0, 0);
        sc[fj] = __builtin_amdgcn_mfma_f32_16x16x32_f16(aqh[ks], bkl, sc[fj], 0, 0, 0);
      }
    }
    if (CAUSAL && kt == qt) {
#pragma unroll
      for (int fj = 0; fj < 4; ++fj)
#pragma unroll
        for (int r = 0; r < 4; ++r)
          if (fj * 16 + l15 > wid * 16 + l4 * 4 + r) sc[fj][r] = -1e20f;
    }
    if (!CAUSAL) {
#pragma unroll
      for (int fj = 0; fj < 4; ++fj)
        if (!((mbits >> (kt * 4 + fj)) & 1u)) {
#pragma unroll
          for (int r = 0; r < 4; ++r) sc[fj][r] = -1e20f;
        }
    }
#pragma unroll
    for (int r = 0; r < 4; ++r) {
      float rm = fmaxf(fmaxf(sc[0][r], sc[1][r]), fmaxf(sc[2][r], sc[3][r]));
#pragma unroll
      for (int mk = 1; mk < 16; mk <<= 1) rm = fmaxf(rm, __shfl_xor(rm, mk));
      float mn = fmaxf(m_[r], rm);
      float f = __expf(m_[r] - mn);
      float rs = 0.f;
      int prow = wid * 16 + l4 * 4 + r;
#pragma unroll
      for (int fj = 0; fj < 4; ++fj) {
        float p = __expf(sc[fj][r] - mn);
        rs += p;
        int col = fj * 16 + l15;
        int el = (prow << 6) + ((((col >> 3) ^ (prow & 7))) << 3) + (col & 7);
        _Float16 ph = (_Float16)p;
        sPh[el] = ph;
        sPl[el] = (_Float16)(p - (float)ph);
      }
#pragma unroll
      for (int mk = 1; mk < 16; mk <<= 1) rs += __shfl_xor(rs, mk);
      l_[r] = l_[r] * f + rs;
      m_[r] = mn;
#pragma unroll
      for (int df = 0; df < 4; ++df) o_[df][r] *= f;
    }
#pragma unroll
    for (int ks = 0; ks < 2; ++ks) {
      int poff = swzel(wid * 16 + l15, ks * 4 + l4);
      h8 aph = *(const h8*)&sPh[poff];
      h8 apl = *(const h8*)&sPl[poff];
#pragma unroll
      for (int df = 0; df < 4; ++df) {
        int voff = swzel(df * 16 + l15, ks * 4 + l4);
        h8 bvh = *(const h8*)&pVh[voff];
        h8 bvl = *(const h8*)&pVl[voff];
        o_[df] = __builtin_amdgcn_mfma_f32_16x16x32_f16(aph, bvh, o_[df], 0, 0, 0);
        o_[df] = __builtin_amdgcn_mfma_f32_16x16x32_f16(apl, bvh, o_[df], 0, 0, 0);
        o_[df] = __builtin_amdgcn_mfma_f32_16x16x32_f16(aph, bvl, o_[df], 0, 0, 0);
      }
    }
    __builtin_amdgcn_sched_barrier(0);
    __builtin_amdgcn_s_barrier();
    cur ^= 1;
  }
#pragma unroll
  for (int r = 0; r < 4; ++r) {
    float inv = 1.0f / l_[r];
    int row = qt * 64 + wid * 16 + l4 * 4 + r;
    size_t ob = ((size_t)b * SS + row) * DD + (bh & 15) * 64;
#pragma unroll
    for (int df = 0; df < 4; ++df) {
      float o = o_[df][r] * inv;
      split16(o, AOh[ob + df * 16 + l15], AOl[ob + df * 16 + l15]);
    }
  }
}

// --------------------------------------------------------------------------
extern "C" void kernel_launch(void* const* d_in, const int* in_sizes, int n_in,
                              void* d_out, int out_size, void* d_ws,
                              size_t ws_size, hipStream_t stream) {
  const int* tokens = (const int*)d_in[0];
  const float* enc = (const float*)d_in[1];
  const int* encmask = (const int*)d_in[2];
  const float* emb = (const float*)d_in[3];
  const float* sa_qw = (const float*)d_in[4];
  const float* sa_qb = (const float*)d_in[5];
  const float* sa_kw = (const float*)d_in[6];
  const float* sa_kb = (const float*)d_in[7];
  const float* sa_vw = (const float*)d_in[8];
  const float* sa_vb = (const float*)d_in[9];
  const float* sa_ow = (const float*)d_in[10];
  const float* sa_ob = (const float*)d_in[11];
  const float* ca_qw = (const float*)d_in[12];
  const float* ca_qb = (const float*)d_in[13];
  const float* ca_kw = (const float*)d_in[14];
  const float* ca_kb = (const float*)d_in[15];
  const float* ca_vw = (const float*)d_in[16];
  const float* ca_vb = (const float*)d_in[17];
  const float* ca_ow = (const float*)d_in[18];
  const float* ca_ob = (const float*)d_in[19];
  const float* ln1_g = (const float*)d_in[20];
  const float* ln1_b = (const float*)d_in[21];
  const float* ln2_g = (const float*)d_in[22];
  const float* ln2_b = (const float*)d_in[23];
  const float* ln3_g = (const float*)d_in[24];
  const float* ln3_b = (const float*)d_in[25];
  const float* ff_w1 = (const float*)d_in[26];
  const float* ff_b1 = (const float*)d_in[27];
  const float* ff_w2 = (const float*)d_in[28];
  const float* ff_b2 = (const float*)d_in[29];
  const float* act_w = (const float*)d_in[30];
  const float* act_b = (const float*)d_in[31];
  float* out = (float*)d_out;

  const size_t nbsd = (size_t)BB * SS * DD;  // 2097152
  const size_t nff = (size_t)BB * SS * FFD;  // 8388608
  const size_t nbs = (size_t)BB * SS;        // 2048
  const size_t wsm = (size_t)DD * DD;
  const size_t wff = (size_t)DD * FFD;

  // ---- fp32 region ----
  float* w = (float*)d_ws;
  float* POS = w;  w += (size_t)SS * DD;
  float* TIM = w;  w += (size_t)NHOP * DD;
  float* TEN = w;  w += nbsd;
  float* PR = w;   w += nbsd;
  float* T2R = w;  w += (size_t)2048 * 3072;  // hosts T2 planes
  float* QKVB = w; w += 3072;
  float* HPp = w;  w += nbs;
  float* REMp = w; w += nbs;
  float* UWp = w;  w += nbs;
  // ---- fp16 region ----
  _Float16* hp16 = (_Float16*)w;
  auto halloc = [&](size_t n) { _Float16* r = hp16; hp16 += n; return r; };
  _Float16* TINh = halloc(nbsd); _Float16* TINl = halloc(nbsd);
  _Float16* AOh = halloc(nbsd);  _Float16* AOl = halloc(nbsd);
  _Float16* FFHh = halloc(nff);  _Float16* FFHl = halloc(nff);
  _Float16* qkvWh = halloc(3 * wsm); _Float16* qkvWl = halloc(3 * wsm);
  _Float16* saoWh = halloc(wsm); _Float16* saoWl = halloc(wsm);
  _Float16* caqWh = halloc(wsm); _Float16* caqWl = halloc(wsm);
  _Float16* caoWh = halloc(wsm); _Float16* caoWl = halloc(wsm);
  _Float16* ff1Wh = halloc(wff); _Float16* ff1Wl = halloc(wff);
  _Float16* ff2Wh = halloc(wff); _Float16* ff2Wl = halloc(wff);
  _Float16* EKh = halloc(nbsd); _Float16* EKl = halloc(nbsd);
  _Float16* EVh = halloc(nbsd); _Float16* EVl = halloc(nbsd);
  size_t need = (size_t)((char*)hp16 - (char*)d_ws);
  if (ws_size < need) return;

  // lifetime-disjoint aliases:
  _Float16* T3h = TINh; _Float16* T3l = TINl;
  _Float16* T2h = (_Float16*)T2R;
  _Float16* T2l = (_Float16*)T2R + nbsd;
  _Float16* Qph = FFHh;             _Float16* Qpl = FFHh + nbsd;
  _Float16* Kph = FFHh + 2 * nbsd;  _Float16* Kpl = FFHh + 3 * nbsd;
  _Float16* Vph = FFHl;             _Float16* Vpl = FFHl + nbsd;
  _Float16* CQh = FFHl + 2 * nbsd;  _Float16* CQl = FFHl + 3 * nbsd;

  hipMemsetAsync(d_out, 0, nbsd * sizeof(float), stream);
  hipMemsetAsync(HPp, 0, 2 * nbs * sizeof(float), stream);
  sincos_kernel<<<dim3(512), dim3(256), 0, stream>>>(POS, SS * DD);
  sincos_kernel<<<dim3(24), dim3(256), 0, stream>>>(TIM, NHOP * DD);
  embed_kernel<<<dim3(2048), dim3(256), 0, stream>>>(tokens, emb, TEN, (int)nbsd);
  asplit_kernel<<<dim3(2048), dim3(256), 0, stream>>>(enc, TINh, TINl, (int)nbsd);

  auto wsplit = [&](const float* W, _Float16* h, _Float16* l, int K, int N) {
    wsplit_kernel<<<dim3(N >> 5, K >> 5), dim3(256), 0, stream>>>(W, h, l, K, N);
  };
  wsplit(sa_qw, qkvWh, qkvWl, DD, DD);
  wsplit(sa_kw, qkvWh + wsm, qkvWl + wsm, DD, DD);
  wsplit(sa_vw, qkvWh + 2 * wsm, qkvWl + 2 * wsm, DD, DD);
  wsplit(sa_ow, saoWh, saoWl, DD, DD);
  wsplit(ca_qw, caqWh, caqWl, DD, DD);
  wsplit(ca_kw, FFHh, FFHh + wsm, DD, DD);              // temp in FFH
  wsplit(ca_vw, FFHh + 2 * wsm, FFHh + 3 * wsm, DD, DD);
  wsplit(ca_ow, caoWh, caoWl, DD, DD);
  wsplit(ff_w1, ff1Wh, ff1Wl, DD, FFD);
  wsplit(ff_w2, ff2Wh, ff2Wl, FFD, DD);
  concat3_kernel<<<dim3(12), dim3(256), 0, stream>>>(sa_qb, sa_kb, sa_vb, QKVB);

  auto gemmF = [&](const _Float16* ah, const _Float16* al, const _Float16* bh,
                   const _Float16* bl, const float* bi, float* cf, int M, int N,
                   int K) {
    gemm_pl<0><<<dim3(N / 64, M / 64), dim3(256), 0, stream>>>(
        ah, al, bh, bl, bi, cf, nullptr, nullptr, nullptr, nullptr, nullptr,
        nullptr, M, N, K, 1.f);
  };

  // hoisted: encoder K -> EK planes; encoder V -> EV transposed planes
  gemm_pl<3><<<dim3(16, 32), dim3(256), 0, stream>>>(
      TINh, TINl, FFHh, FFHh + wsm, ca_kb, nullptr, EKh, EKl, nullptr, nullptr,
      nullptr, nullptr, 2048, DD, DD, 1.f);
  gemm_pl<4><<<dim3(16, 32), dim3(256), 0, stream>>>(
      TINh, TINl, FFHh + 2 * wsm, FFHh + 3 * wsm, ca_vb, nullptr, EVh, EVl,
      nullptr, nullptr, nullptr, nullptr, 2048, DD, DD, 1.f);

  for (int t = 0; t < NHOP; ++t) {
    actcodes_kernel<<<dim3(2048), dim3(256), 0, stream>>>(
        TEN, POS, TIM, t, act_w, act_b, HPp, REMp, UWp, TINh, TINl);
    // fused QKV projection: 128x64 tile, grid (48,16)=768 (3/CU)
    gemm_big<2><<<dim3(48, 16), dim3(256), 0, stream>>>(
        TINh, TINl, qkvWh, qkvWl, QKVB, Qph, Qpl, Kph, Kpl, Vph, Vpl, 2048,
        3072, DD, 0.125f);
    flash_mfma<1><<<dim3(512), dim3(256), 0, stream>>>(
        Qph, Qpl, Kph, Kpl, Vph, Vpl, AOh, AOl, nullptr, SS);
    gemmF(AOh, AOl, saoWh, saoWl, sa_ob, PR, 2048, DD, DD);
    lnres_kernel<<<dim3(2048), dim3(256), 0, stream>>>(
        PR, TINh, TINl, ln1_g, ln1_b, nullptr, T2h, T2l, nullptr, nullptr, 1);
    gemm_pl<3><<<dim3(16, 32), dim3(256), 0, stream>>>(
        T2h, T2l, caqWh, caqWl, ca_qb, nullptr, CQh, CQl, nullptr, nullptr,
        nullptr, nullptr, 2048, DD, DD, 0.125f);
    flash_mfma<0><<<dim3(512), dim3(256), 0, stream>>>(
        CQh, CQl, EKh, EKl, EVh, EVl, AOh, AOl, encmask, SE);
    gemmF(AOh, AOl, caoWh, caoWl, ca_ob, PR, 2048, DD, DD);
    lnres_kernel<<<dim3(2048), dim3(256), 0, stream>>>(
        PR, T2h, T2l, ln2_g, ln2_b, nullptr, T3h, T3l, nullptr, nullptr, 1);
    // FFN: ff1 128x64 tile grid (64,16)=1024 (4/CU); ff2 64x64 grid 512
    gemm_big<1><<<dim3(64, 16), dim3(256), 0, stream>>>(
        T3h, T3l, ff1Wh, ff1Wl, ff_b1, FFHh, FFHl, nullptr, nullptr, nullptr,
        nullptr, 2048, FFD, DD, 1.f);
    gemmF(FFHh, FFHl, ff2Wh, ff2Wl, ff_b2, PR, 2048, DD, FFD);
    lnres_kernel<<<dim3(2048), dim3(256), 0, stream>>>(
        PR, T3h, T3l, ln3_g, ln3_b, TEN, nullptr, nullptr, UWp, out, 0);
  }
}

// Round 12
// 2015.276 us; speedup vs baseline: 1.4039x; 1.4039x over previous
//
#include <hip/hip_runtime.h>
#include <math.h>

#define BB 4
#define SS 512
#define SE 512
#define DD 1024
#define HH 16
#define FFD 4096
#define NHOP 6

typedef float f32x4 __attribute__((ext_vector_type(4)));
typedef _Float16 h8 __attribute__((ext_vector_type(8)));
typedef _Float16 h4 __attribute__((ext_vector_type(4)));

#define GLD16(gp, lp)                                                     \
  __builtin_amdgcn_global_load_lds(                                       \
      (const __attribute__((address_space(1))) void*)(gp),                \
      (__attribute__((address_space(3))) void*)(lp), 16, 0, 0)

template <int N>
__device__ __forceinline__ void vwait() {
  if constexpr (N == 0) asm volatile("s_waitcnt vmcnt(0)" ::: "memory");
  else if constexpr (N == 6) asm volatile("s_waitcnt vmcnt(6)" ::: "memory");
  else if constexpr (N == 8) asm volatile("s_waitcnt vmcnt(8)" ::: "memory");
}

// ---------------- block reduction (256 threads = 4 waves) ----------------
__device__ __forceinline__ float blockSum256(float v, float* s4) {
#pragma unroll
  for (int m = 32; m >= 1; m >>= 1) v += __shfl_xor(v, m);
  __syncthreads();
  if ((threadIdx.x & 63) == 0) s4[threadIdx.x >> 6] = v;
  __syncthreads();
  return s4[0] + s4[1] + s4[2] + s4[3];
}

__device__ __forceinline__ void split16(float v, _Float16& h, _Float16& l) {
  h = (_Float16)v;
  l = (_Float16)(v - (float)h);
}

// swizzled LDS element offset for [64 rows][8 slots of 8 fp16] (BK=64 tiles)
__device__ __forceinline__ int swzel(int row, int slot) {
  return (row << 6) + ((slot ^ (row & 7)) << 3);
}

// ---------------- sincos position/time codes (fp64, matches numpy) -------
__global__ void sincos_kernel(float* __restrict__ out, int n) {
  for (int i = blockIdx.x * blockDim.x + threadIdx.x; i < n;
       i += gridDim.x * blockDim.x) {
    int p = i >> 10, d = i & 1023, j = d >> 1;
    double ang = (double)p / pow(10000.0, (2.0 * j) / 1024.0);
    out[i] = (float)((d & 1) ? cos(ang) : sin(ang));
  }
}

// ---------------- embedding gather * sqrt(D) ------------------------------
__global__ void embed_kernel(const int* __restrict__ tok,
                             const float* __restrict__ emb,
                             float* __restrict__ out, int n) {
  for (int i = blockIdx.x * blockDim.x + threadIdx.x; i < n;
       i += gridDim.x * blockDim.x) {
    int row = i >> 10, d = i & 1023;
    out[i] = emb[(size_t)tok[row] * DD + d] * 32.0f;
  }
}

// ---------------- fp32 -> hi/lo fp16 planes (same layout) ----------------
__global__ void asplit_kernel(const float* __restrict__ x,
                              _Float16* __restrict__ h,
                              _Float16* __restrict__ l, int n) {
  for (int i = blockIdx.x * blockDim.x + threadIdx.x; i < n;
       i += gridDim.x * blockDim.x)
    split16(x[i], h[i], l[i]);
}

// ---------------- fused: tensor+codes -> TIN planes AND ACT halting ------
__global__ __launch_bounds__(256)
void actcodes_kernel(const float* __restrict__ ten, const float* __restrict__ pos,
                     const float* __restrict__ tim, int hop,
                     const float* __restrict__ aw, const float* __restrict__ ab,
                     float* __restrict__ hp, float* __restrict__ rem,
                     float* __restrict__ uw, _Float16* __restrict__ th,
                     _Float16* __restrict__ tl) {
  __shared__ float s4[4];
  int row = blockIdx.x;
  int srow = row & 511;
  size_t base = (size_t)row * DD;
  float s = 0.f;
#pragma unroll
  for (int k = 0; k < 4; ++k) {
    int d = threadIdx.x + k * 256;
    float v = ten[base + d] + pos[(srow << 10) + d] + tim[(hop << 10) + d];
    split16(v, th[base + d], tl[base + d]);
    s += v * aw[d];
  }
  float z = blockSum256(s, s4);
  if (threadIdx.x == 0) {
    z += ab[0];
    float p = 1.0f / (1.0f + expf(-z));
    float h = hp[row], rm = rem[row];
    float s0 = (h < 1.0f) ? 1.0f : 0.0f;
    float cond = h + p * s0;
    float nh = (cond > 0.99f) ? s0 : 0.0f;
    float s1 = (cond <= 0.99f) ? s0 : 0.0f;
    h = h + p * s1;
    rm = rm + nh * (1.0f - h);
    h = h + nh * rm;
    hp[row] = h;
    rem[row] = rm;
    uw[row] = p * s1 + nh * rm;
  }
}

// ---------------- fused residual + LayerNorm (+ optional prev update) ----
__global__ __launch_bounds__(256)
void lnres_kernel(const float* __restrict__ a, const _Float16* __restrict__ rh,
                  const _Float16* __restrict__ rl, const float* __restrict__ g,
                  const float* __restrict__ be, float* __restrict__ outf,
                  _Float16* __restrict__ oh, _Float16* __restrict__ ol,
                  const float* __restrict__ uwv, float* __restrict__ po,
                  int mode) {
  __shared__ float s4[4];
  int row = blockIdx.x;
  size_t base = (size_t)row * DD;
  float x[4];
#pragma unroll
  for (int k = 0; k < 4; ++k) {
    size_t idx = base + threadIdx.x + k * 256;
    x[k] = a[idx] + ((float)rh[idx] + (float)rl[idx]);
  }
  float mean = blockSum256(x[0] + x[1] + x[2] + x[3], s4) * (1.0f / 1024.0f);
  float q = 0.f;
#pragma unroll
  for (int k = 0; k < 4; ++k) {
    float dv = x[k] - mean;
    q += dv * dv;
  }
  float var = blockSum256(q, s4) * (1.0f / 1024.0f);
  float inv = 1.0f / sqrtf(var + 1e-12f);
  float u = (mode == 0) ? uwv[row] : 0.f;
#pragma unroll
  for (int k = 0; k < 4; ++k) {
    int d = threadIdx.x + k * 256;
    size_t idx = base + d;
    float y = (x[k] - mean) * inv * g[d] + be[d];
    if (mode == 0) {
      outf[idx] = y;
      po[idx] = y * u + po[idx] * (1.0f - u);  // prev update fused
    } else {
      split16(y, oh[idx], ol[idx]);
    }
  }
}

// ---------------- weight transpose + fp16 hi/lo split --------------------
__global__ __launch_bounds__(256)
void wsplit_kernel(const float* __restrict__ W, _Float16* __restrict__ WhT,
                   _Float16* __restrict__ WlT, int K, int N) {
  __shared__ float t[32][33];
  int k0 = blockIdx.y << 5, n0 = blockIdx.x << 5;
  int c = threadIdx.x & 31, r8 = threadIdx.x >> 5;
  for (int rr = r8; rr < 32; rr += 8)
    t[rr][c] = W[(size_t)(k0 + rr) * N + n0 + c];
  __syncthreads();
  for (int rr = r8; rr < 32; rr += 8) {
    float v = t[c][rr];
    split16(v, WhT[(size_t)(n0 + rr) * K + k0 + c],
            WlT[(size_t)(n0 + rr) * K + k0 + c]);
  }
}

// ---------------- concat 3 bias vectors ----------------------------------
__global__ void concat3_kernel(const float* __restrict__ a,
                               const float* __restrict__ b,
                               const float* __restrict__ c,
                               float* __restrict__ o) {
  int i = blockIdx.x * 256 + threadIdx.x;
  if (i < 3072) o[i] = (i < 1024) ? a[i] : ((i < 2048) ? b[i - 1024] : c[i - 2048]);
}

// ---------------- DD-size split-fp16 MFMA GEMM (64x64, BK=64) ------------
// Both operands via gload_lds (R10-verified). EPI 0: fp32 out. EPI 1: relu
// -> planes. EPI 3: head-blocked planes*scale. EPI 4: Vt planes only.
template <int EPI>
__global__ __launch_bounds__(256) void gemm_pl(
    const _Float16* __restrict__ Ah, const _Float16* __restrict__ Al,
    const _Float16* __restrict__ Bh, const _Float16* __restrict__ Bl,
    const float* __restrict__ bias, float* __restrict__ Cf,
    _Float16* __restrict__ Ch, _Float16* __restrict__ Cl,
    _Float16* __restrict__ Ch2, _Float16* __restrict__ Cl2,
    _Float16* __restrict__ Ch3, _Float16* __restrict__ Cl3, int M, int N,
    int K, float scale) {
  __shared__ __align__(16) _Float16 sA0[2][4096], sA1[2][4096];
  __shared__ __align__(16) _Float16 sB0[2][4096], sB1[2][4096];
  const int tid = threadIdx.x;
  const int lane = tid & 63, wid = tid >> 6;
  const int wr = wid >> 1, wc = wid & 1;
  int bx = blockIdx.x, by = blockIdx.y;
  {
    int nb = gridDim.x * gridDim.y;
    if ((nb & 7) == 0) {
      int flat = by * gridDim.x + bx;
      int swz = (flat & 7) * (nb >> 3) + (flat >> 3);
      bx = swz % gridDim.x;
      by = swz / gridDim.x;
    }
  }
  const int m0 = by << 6, n0 = bx << 6;
  const int l15 = lane & 15, l4 = lane >> 4;

  f32x4 acc[2][2];
#pragma unroll
  for (int i = 0; i < 2; ++i)
#pragma unroll
    for (int j = 0; j < 2; ++j) acc[i][j] = (f32x4){0.f, 0.f, 0.f, 0.f};

  auto STAGE = [&](int kt, int buf) {
    const int ko = kt << 6;
#pragma unroll
    for (int c = 0; c < 2; ++c) {
      int idx = (c << 8) + tid;
      int row = idx >> 3, gs = (idx & 7) ^ (row & 7);
      int de = (c << 11) + (wid << 9);
      size_t ga = (size_t)(m0 + row) * K + ko + (gs << 3);
      GLD16(Ah + ga, &sA0[buf][de]);
      GLD16(Al + ga, &sA1[buf][de]);
      size_t gb = (size_t)(n0 + row) * K + ko + (gs << 3);
      GLD16(Bh + gb, &sB0[buf][de]);
      GLD16(Bl + gb, &sB1[buf][de]);
    }
  };

  const int nk = K >> 6;
  STAGE(0, 0);
  int cur = 0;
  for (int kt = 0; kt < nk; ++kt) {
    if (kt + 1 < nk) {
      STAGE(kt + 1, cur ^ 1);
      vwait<8>();
    } else {
      vwait<0>();
    }
    __builtin_amdgcn_s_barrier();
    __builtin_amdgcn_sched_barrier(0);
    const _Float16* pA0 = sA0[cur];
    const _Float16* pA1 = sA1[cur];
    const _Float16* pB0 = sB0[cur];
    const _Float16* pB1 = sB1[cur];
#pragma unroll
    for (int ks = 0; ks < 2; ++ks) {
      h8 a0[2], a1[2], b0[2], b1[2];
#pragma unroll
      for (int f = 0; f < 2; ++f) {
        int m = (wr << 5) + (f << 4) + l15;
        int so = swzel(m, (ks << 2) + l4);
        a0[f] = *(const h8*)&pA0[so];
        a1[f] = *(const h8*)&pA1[so];
        int n = (wc << 5) + (f << 4) + l15;
        int sn = swzel(n, (ks << 2) + l4);
        b0[f] = *(const h8*)&pB0[sn];
        b1[f] = *(const h8*)&pB1[sn];
      }
#pragma unroll
      for (int fi = 0; fi < 2; ++fi)
#pragma unroll
        for (int fj = 0; fj < 2; ++fj) {
          acc[fi][fj] = __builtin_amdgcn_mfma_f32_16x16x32_f16(
              a0[fi], b0[fj], acc[fi][fj], 0, 0, 0);
          acc[fi][fj] = __builtin_amdgcn_mfma_f32_16x16x32_f16(
              a1[fi], b0[fj], acc[fi][fj], 0, 0, 0);
          acc[fi][fj] = __builtin_amdgcn_mfma_f32_16x16x32_f16(
              a0[fi], b1[fj], acc[fi][fj], 0, 0, 0);
        }
    }
    __builtin_amdgcn_sched_barrier(0);
    __builtin_amdgcn_s_barrier();
    cur ^= 1;
  }
#pragma unroll
  for (int fi = 0; fi < 2; ++fi) {
    int row = m0 + (wr << 5) + (fi << 4) + (l4 << 2);
#pragma unroll
    for (int fj = 0; fj < 2; ++fj) {
      int col = n0 + (wc << 5) + (fj << 4) + l15;
      float bz = bias[col];
      float ov[4];
#pragma unroll
      for (int r = 0; r < 4; ++r) ov[r] = acc[fi][fj][r] + bz;
      if (EPI == 0) {
#pragma unroll
        for (int r = 0; r < 4; ++r) Cf[(size_t)(row + r) * N + col] = ov[r];
      } else if (EPI == 1) {
#pragma unroll
        for (int r = 0; r < 4; ++r) {
          float o = fmaxf(ov[r], 0.f);
          size_t idx = (size_t)(row + r) * N + col;
          split16(o, Ch[idx], Cl[idx]);
        }
      } else if (EPI == 3) {
        int b = row >> 9, h = col >> 6, d = col & 63;
#pragma unroll
        for (int r = 0; r < 4; ++r) {
          int sr = (row + r) & 511;
          size_t q = ((size_t)(b * HH + h) * SS + sr) * 64 + d;
          split16(ov[r] * scale, Ch[q], Cl[q]);
        }
      } else if (EPI == 4) {  // V transposed planes: Vt[bh][d][s]
        int b = row >> 9, s0 = row & 511, h = col >> 6, d = col & 63;
        h4 hv, lv;
#pragma unroll
        for (int r = 0; r < 4; ++r) {
          _Float16 hh, ll;
          split16(ov[r], hh, ll);
          hv[r] = hh;
          lv[r] = ll;
        }
        size_t vo = ((size_t)(b * HH + h) * 64 + d) * SS + s0;
        *(h4*)&Ch[vo] = hv;
        *(h4*)&Cl[vo] = lv;
      }
    }
  }
}

// ---------------- big-N split-fp16 MFMA GEMM (128x64 tile, BK=32) --------
// R7-proven staging/swizzle. EPI 1: relu -> planes. EPI 2: QKV dispatch
// (Q/K head planes + Vt planes).
template <int EPI>
__global__ __launch_bounds__(256) void gemm_big(
    const _Float16* __restrict__ Ah, const _Float16* __restrict__ Al,
    const _Float16* __restrict__ Bh, const _Float16* __restrict__ Bl,
    const float* __restrict__ bias, _Float16* __restrict__ Ch,
    _Float16* __restrict__ Cl, _Float16* __restrict__ Ch2,
    _Float16* __restrict__ Cl2, _Float16* __restrict__ Ch3,
    _Float16* __restrict__ Cl3, int M, int N, int K, float scale) {
  constexpr int FM = 4, FN = 2;
  constexpr int MT = 128, NT = 64;
  constexpr int SA = 2, SB = 1;   // 16B chunks/thread/plane
  constexpr int L = 2 * (SA + SB);
  __shared__ __align__(16) _Float16 sA0[2][MT * 32], sA1[2][MT * 32];
  __shared__ __align__(16) _Float16 sB0[2][NT * 32], sB1[2][NT * 32];
  const int tid = threadIdx.x;
  const int lane = tid & 63, wid = tid >> 6;
  const int wr = wid >> 1, wc = wid & 1;
  int bx = blockIdx.x, by = blockIdx.y;
  {
    int nb = gridDim.x * gridDim.y;
    if ((nb & 7) == 0) {
      int flat = by * gridDim.x + bx;
      int swz = (flat & 7) * (nb >> 3) + (flat >> 3);
      bx = swz % gridDim.x;
      by = swz / gridDim.x;
    }
  }
  const int m0 = by * MT, n0 = bx * NT;
  const int l15 = lane & 15, l4 = lane >> 4;

  f32x4 acc[FM][FN];
#pragma unroll
  for (int i = 0; i < FM; ++i)
#pragma unroll
    for (int j = 0; j < FN; ++j) acc[i][j] = (f32x4){0.f, 0.f, 0.f, 0.f};

  auto STAGE = [&](int kt, int buf) {
    const int ko = kt << 5;
#pragma unroll
    for (int c = 0; c < SA; ++c) {
      int slot = tid + (c << 8);
      int row = slot >> 2, sl = slot & 3;
      int of = ((sl ^ ((row >> 1) & 3)) << 3);
      size_t ga = (size_t)(m0 + row) * K + ko + of;
      int de = (wid << 9) + (c << 11);
      GLD16(Ah + ga, &sA0[buf][de]);
      GLD16(Al + ga, &sA1[buf][de]);
    }
#pragma unroll
    for (int c = 0; c < SB; ++c) {
      int slot = tid + (c << 8);
      int row = slot >> 2, sl = slot & 3;
      int of = ((sl ^ ((row >> 1) & 3)) << 3);
      size_t gb = (size_t)(n0 + row) * K + ko + of;
      int de = (wid << 9) + (c << 11);
      GLD16(Bh + gb, &sB0[buf][de]);
      GLD16(Bl + gb, &sB1[buf][de]);
    }
  };

  const int nk = K >> 5;
  STAGE(0, 0);
  int cur = 0;
  for (int kt = 0; kt < nk; ++kt) {
    if (kt + 1 < nk) {
      STAGE(kt + 1, cur ^ 1);
      vwait<L>();
    } else {
      vwait<0>();
    }
    __builtin_amdgcn_s_barrier();
    __builtin_amdgcn_sched_barrier(0);
    const _Float16* pA0 = sA0[cur];
    const _Float16* pA1 = sA1[cur];
    const _Float16* pB0 = sB0[cur];
    const _Float16* pB1 = sB1[cur];
    h8 a0[FM], a1[FM], b0[FN], b1[FN];
#pragma unroll
    for (int f = 0; f < FM; ++f) {
      int m = wr * (FM * 16) + f * 16 + l15;
      int st = ((l4 ^ ((m >> 1) & 3)) << 3);
      a0[f] = *(const h8*)&pA0[(m << 5) + st];
      a1[f] = *(const h8*)&pA1[(m << 5) + st];
    }
#pragma unroll
    for (int f = 0; f < FN; ++f) {
      int n = wc * (FN * 16) + f * 16 + l15;
      int sn = ((l4 ^ ((n >> 1) & 3)) << 3);
      b0[f] = *(const h8*)&pB0[(n << 5) + sn];
      b1[f] = *(const h8*)&pB1[(n << 5) + sn];
    }
#pragma unroll
    for (int fi = 0; fi < FM; ++fi)
#pragma unroll
      for (int fj = 0; fj < FN; ++fj) {
        acc[fi][fj] = __builtin_amdgcn_mfma_f32_16x16x32_f16(
            a0[fi], b0[fj], acc[fi][fj], 0, 0, 0);
        acc[fi][fj] = __builtin_amdgcn_mfma_f32_16x16x32_f16(
            a1[fi], b0[fj], acc[fi][fj], 0, 0, 0);
        acc[fi][fj] = __builtin_amdgcn_mfma_f32_16x16x32_f16(
            a0[fi], b1[fj], acc[fi][fj], 0, 0, 0);
      }
    __builtin_amdgcn_sched_barrier(0);
    __builtin_amdgcn_s_barrier();
    cur ^= 1;
  }
#pragma unroll
  for (int fi = 0; fi < FM; ++fi) {
    int row = m0 + wr * (FM * 16) + fi * 16 + (l4 << 2);
#pragma unroll
    for (int fj = 0; fj < FN; ++fj) {
      int col = n0 + wc * (FN * 16) + fj * 16 + l15;
      float bz = bias[col];
      float ov[4];
#pragma unroll
      for (int r = 0; r < 4; ++r) ov[r] = acc[fi][fj][r] + bz;
      if (EPI == 1) {
#pragma unroll
        for (int r = 0; r < 4; ++r) {
          float o = fmaxf(ov[r], 0.f);
          size_t idx = (size_t)(row + r) * N + col;
          split16(o, Ch[idx], Cl[idx]);
        }
      } else {  // EPI == 2: QKV dispatch (Q planes, K planes, Vt planes)
        int reg = col >> 10;  // wave-uniform per block (NT=64 divides 1024)
        int c = col & 1023;
        int b = row >> 9, h = c >> 6, d = c & 63;
        if (reg == 2) {
          int s0 = row & 511;
          h4 hv, lv;
#pragma unroll
          for (int r = 0; r < 4; ++r) {
            _Float16 hh, ll;
            split16(ov[r], hh, ll);
            hv[r] = hh;
            lv[r] = ll;
          }
          size_t vo = ((size_t)(b * HH + h) * 64 + d) * SS + s0;
          *(h4*)&Ch3[vo] = hv;
          *(h4*)&Cl3[vo] = lv;
        } else {
#pragma unroll
          for (int r = 0; r < 4; ++r) {
            float o = (reg == 0) ? ov[r] * scale : ov[r];
            int sr = (row + r) & 511;
            size_t q = ((size_t)(b * HH + h) * SS + sr) * 64 + d;
            if (reg == 0) split16(o, Ch[q], Cl[q]);
            else split16(o, Ch2[q], Cl2[q]);
          }
        }
      }
    }
  }
}

// ---------------- MFMA flash attention (counted-vmcnt pipelined) ---------
// XCD-chunked block mapping: same-bh blocks land on the same XCD L2.
template <int CAUSAL>
__global__ __launch_bounds__(256) void flash_mfma(
    const _Float16* __restrict__ Qph, const _Float16* __restrict__ Qpl,
    const _Float16* __restrict__ Kph, const _Float16* __restrict__ Kpl,
    const _Float16* __restrict__ Vph, const _Float16* __restrict__ Vpl,
    _Float16* __restrict__ AOh, _Float16* __restrict__ AOl,
    const int* __restrict__ mask, int Sk) {
  __shared__ __align__(16) _Float16 sKh[2][4096], sKl[2][4096];
  __shared__ __align__(16) _Float16 sVh[2][4096], sVl[2][4096];
  __shared__ __align__(16) _Float16 sPh[4096], sPl[4096];
  const int tid = threadIdx.x, lane = tid & 63, wid = tid >> 6;
  const int l15 = lane & 15, l4 = lane >> 4;
  // XCD-chunked: H mod 8 = XCD; give each XCD 8 full bh groups (512 blocks)
  const int H = blockIdx.x;
  const int flat = (H & 7) * 64 + (H >> 3);
  const int bh = flat >> 3, b = bh >> 4;
  const int qt = flat & 7;
  const size_t qkb = (size_t)bh * SS * 64;
  const size_t vtb = (size_t)bh * 64 * Sk;

  int srow[2], slg[2], sde[2];
#pragma unroll
  for (int c = 0; c < 2; ++c) {
    int u = (c << 8) + tid;
    srow[c] = u >> 3;
    slg[c] = (u & 7) ^ (srow[c] & 7);
    sde[c] = (c << 11) + (wid << 9);
  }

  unsigned mbits = 0xFFFFFFFFu;
  if (!CAUSAL && mask != nullptr) {
    mbits = 0u;
#pragma unroll
    for (int kt = 0; kt < 8; ++kt)
#pragma unroll
      for (int fj = 0; fj < 4; ++fj)
        mbits |= (mask[b * Sk + kt * 64 + fj * 16 + l15] != 0 ? 1u : 0u)
                 << (kt * 4 + fj);
  }

  h8 aqh[2], aql[2];
#pragma unroll
  for (int ks = 0; ks < 2; ++ks) {
    size_t qa = qkb + (size_t)(qt * 64 + wid * 16 + l15) * 64 + ks * 32 + l4 * 8;
    aqh[ks] = *(const h8*)(Qph + qa);
    aql[ks] = *(const h8*)(Qpl + qa);
  }
  f32x4 o_[4];
  float m_[4], l_[4];
#pragma unroll
  for (int i = 0; i < 4; ++i) o_[i] = (f32x4){0.f, 0.f, 0.f, 0.f};
#pragma unroll
  for (int r = 0; r < 4; ++r) { m_[r] = -3.0e38f; l_[r] = 0.f; }

  auto STAGE = [&](int kt, int buf) {
#pragma unroll
    for (int c = 0; c < 2; ++c) {
      size_t ksrc = qkb + (size_t)(kt * 64 + srow[c]) * 64 + slg[c] * 8;
      size_t vsrc = vtb + (size_t)srow[c] * Sk + kt * 64 + slg[c] * 8;
      GLD16(Kph + ksrc, &sKh[buf][sde[c]]);
      GLD16(Kpl + ksrc, &sKl[buf][sde[c]]);
      GLD16(Vph + vsrc, &sVh[buf][sde[c]]);
      GLD16(Vpl + vsrc, &sVl[buf][sde[c]]);
    }
  };

  const int nkt = CAUSAL ? (qt + 1) : (Sk >> 6);
  STAGE(0, 0);
  int cur = 0;
  for (int kt = 0; kt < nkt; ++kt) {
    if (kt + 1 < nkt) {
      STAGE(kt + 1, cur ^ 1);
      vwait<8>();
    } else {
      vwait<0>();
    }
    __builtin_amdgcn_s_barrier();
    __builtin_amdgcn_sched_barrier(0);
    const _Float16* pKh = sKh[cur];
    const _Float16* pKl = sKl[cur];
    const _Float16* pVh = sVh[cur];
    const _Float16* pVl = sVl[cur];
    f32x4 sc[4];
#pragma unroll
    for (int fj = 0; fj < 4; ++fj) {
      sc[fj] = (f32x4){0.f, 0.f, 0.f, 0.f};
#pragma unroll
      for (int ks = 0; ks < 2; ++ks) {
        int off = swzel(fj * 16 + l15, ks * 4 + l4);
        h8 bkh = *(const h8*)&pKh[off];
        h8 bkl = *(const h8*)&pKl[off];
        sc[fj] = __builtin_amdgcn_mfma_f32_16x16x32_f16(aqh[ks], bkh, sc[fj], 0, 0, 0);
        sc[fj] = __builtin_amdgcn_mfma_f32_16x16x32_f16(aql[ks], bkh, sc[fj], 0, 0, 0);
        sc[fj] = __builtin_amdgcn_mfma_f32_16x16x32_f16(aqh[ks], bkl, sc[fj], 0, 0, 0);
      }
    }
    if (CAUSAL && kt == qt) {
#pragma unroll
      for (int fj = 0; fj < 4; ++fj)
#pragma unroll
        for (int r = 0; r < 4; ++r)
          if (fj * 16 + l15 > wid * 16 + l4 * 4 + r) sc[fj][r] = -1e20f;
    }
    if (!CAUSAL) {
#pragma unroll
      for (int fj = 0; fj < 4; ++fj)
        if (!((mbits >> (kt * 4 + fj)) & 1u)) {
#pragma unroll
          for (int r = 0; r < 4; ++r) sc[fj][r] = -1e20f;
        }
    }
#pragma unroll
    for (int r = 0; r < 4; ++r) {
      float rm = fmaxf(fmaxf(sc[0][r], sc[1][r]), fmaxf(sc[2][r], sc[3][r]));
#pragma unroll
      for (int mk = 1; mk < 16; mk <<= 1) rm = fmaxf(rm, __shfl_xor(rm, mk));
      float mn = fmaxf(m_[r], rm);
      float f = __expf(m_[r] - mn);
      float rs = 0.f;
      int prow = wid * 16 + l4 * 4 + r;
#pragma unroll
      for (int fj = 0; fj < 4; ++fj) {
        float p = __expf(sc[fj][r] - mn);
        rs += p;
        int col = fj * 16 + l15;
        int el = (prow << 6) + ((((col >> 3) ^ (prow & 7))) << 3) + (col & 7);
        _Float16 ph = (_Float16)p;
        sPh[el] = ph;
        sPl[el] = (_Float16)(p - (float)ph);
      }
#pragma unroll
      for (int mk = 1; mk < 16; mk <<= 1) rs += __shfl_xor(rs, mk);
      l_[r] = l_[r] * f + rs;
      m_[r] = mn;
#pragma unroll
      for (int df = 0; df < 4; ++df) o_[df][r] *= f;
    }
#pragma unroll
    for (int ks = 0; ks < 2; ++ks) {
      int poff = swzel(wid * 16 + l15, ks * 4 + l4);
      h8 aph = *(const h8*)&sPh[poff];
      h8 apl = *(const h8*)&sPl[poff];
#pragma unroll
      for (int df = 0; df < 4; ++df) {
        int voff = swzel(df * 16 + l15, ks * 4 + l4);
        h8 bvh = *(const h8*)&pVh[voff];
        h8 bvl = *(const h8*)&pVl[voff];
        o_[df] = __builtin_amdgcn_mfma_f32_16x16x32_f16(aph, bvh, o_[df], 0, 0, 0);
        o_[df] = __builtin_amdgcn_mfma_f32_16x16x32_f16(apl, bvh, o_[df], 0, 0, 0);
        o_[df] = __builtin_amdgcn_mfma_f32_16x16x32_f16(aph, bvl, o_[df], 0, 0, 0);
      }
    }
    __builtin_amdgcn_sched_barrier(0);
    __builtin_amdgcn_s_barrier();
    cur ^= 1;
  }
#pragma unroll
  for (int r = 0; r < 4; ++r) {
    float inv = 1.0f / l_[r];
    int row = qt * 64 + wid * 16 + l4 * 4 + r;
    size_t ob = ((size_t)b * SS + row) * DD + (bh & 15) * 64;
#pragma unroll
    for (int df = 0; df < 4; ++df) {
      float o = o_[df][r] * inv;
      split16(o, AOh[ob + df * 16 + l15], AOl[ob + df * 16 + l15]);
    }
  }
}

// --------------------------------------------------------------------------
extern "C" void kernel_launch(void* const* d_in, const int* in_sizes, int n_in,
                              void* d_out, int out_size, void* d_ws,
                              size_t ws_size, hipStream_t stream) {
  const int* tokens = (const int*)d_in[0];
  const float* enc = (const float*)d_in[1];
  const int* encmask = (const int*)d_in[2];
  const float* emb = (const float*)d_in[3];
  const float* sa_qw = (const float*)d_in[4];
  const float* sa_qb = (const float*)d_in[5];
  const float* sa_kw = (const float*)d_in[6];
  const float* sa_kb = (const float*)d_in[7];
  const float* sa_vw = (const float*)d_in[8];
  const float* sa_vb = (const float*)d_in[9];
  const float* sa_ow = (const float*)d_in[10];
  const float* sa_ob = (const float*)d_in[11];
  const float* ca_qw = (const float*)d_in[12];
  const float* ca_qb = (const float*)d_in[13];
  const float* ca_kw = (const float*)d_in[14];
  const float* ca_kb = (const float*)d_in[15];
  const float* ca_vw = (const float*)d_in[16];
  const float* ca_vb = (const float*)d_in[17];
  const float* ca_ow = (const float*)d_in[18];
  const float* ca_ob = (const float*)d_in[19];
  const float* ln1_g = (const float*)d_in[20];
  const float* ln1_b = (const float*)d_in[21];
  const float* ln2_g = (const float*)d_in[22];
  const float* ln2_b = (const float*)d_in[23];
  const float* ln3_g = (const float*)d_in[24];
  const float* ln3_b = (const float*)d_in[25];
  const float* ff_w1 = (const float*)d_in[26];
  const float* ff_b1 = (const float*)d_in[27];
  const float* ff_w2 = (const float*)d_in[28];
  const float* ff_b2 = (const float*)d_in[29];
  const float* act_w = (const float*)d_in[30];
  const float* act_b = (const float*)d_in[31];
  float* out = (float*)d_out;

  const size_t nbsd = (size_t)BB * SS * DD;  // 2097152
  const size_t nff = (size_t)BB * SS * FFD;  // 8388608
  const size_t nbs = (size_t)BB * SS;        // 2048
  const size_t wsm = (size_t)DD * DD;
  const size_t wff = (size_t)DD * FFD;

  // ---- fp32 region ----
  float* w = (float*)d_ws;
  float* POS = w;  w += (size_t)SS * DD;
  float* TIM = w;  w += (size_t)NHOP * DD;
  float* TEN = w;  w += nbsd;
  float* PR = w;   w += nbsd;
  float* T2R = w;  w += (size_t)2048 * 3072;  // hosts T2 planes
  float* QKVB = w; w += 3072;
  float* HPp = w;  w += nbs;
  float* REMp = w; w += nbs;
  float* UWp = w;  w += nbs;
  // ---- fp16 region ----
  _Float16* hp16 = (_Float16*)w;
  auto halloc = [&](size_t n) { _Float16* r = hp16; hp16 += n; return r; };
  _Float16* TINh = halloc(nbsd); _Float16* TINl = halloc(nbsd);
  _Float16* AOh = halloc(nbsd);  _Float16* AOl = halloc(nbsd);
  _Float16* FFHh = halloc(nff);  _Float16* FFHl = halloc(nff);
  _Float16* qkvWh = halloc(3 * wsm); _Float16* qkvWl = halloc(3 * wsm);
  _Float16* saoWh = halloc(wsm); _Float16* saoWl = halloc(wsm);
  _Float16* caqWh = halloc(wsm); _Float16* caqWl = halloc(wsm);
  _Float16* caoWh = halloc(wsm); _Float16* caoWl = halloc(wsm);
  _Float16* ff1Wh = halloc(wff); _Float16* ff1Wl = halloc(wff);
  _Float16* ff2Wh = halloc(wff); _Float16* ff2Wl = halloc(wff);
  _Float16* EKh = halloc(nbsd); _Float16* EKl = halloc(nbsd);
  _Float16* EVh = halloc(nbsd); _Float16* EVl = halloc(nbsd);
  size_t need = (size_t)((char*)hp16 - (char*)d_ws);
  if (ws_size < need) return;

  // lifetime-disjoint aliases:
  _Float16* T3h = TINh; _Float16* T3l = TINl;
  _Float16* T2h = (_Float16*)T2R;
  _Float16* T2l = (_Float16*)T2R + nbsd;
  _Float16* Qph = FFHh;             _Float16* Qpl = FFHh + nbsd;
  _Float16* Kph = FFHh + 2 * nbsd;  _Float16* Kpl = FFHh + 3 * nbsd;
  _Float16* Vph = FFHl;             _Float16* Vpl = FFHl + nbsd;
  _Float16* CQh = FFHl + 2 * nbsd;  _Float16* CQl = FFHl + 3 * nbsd;

  hipMemsetAsync(d_out, 0, nbsd * sizeof(float), stream);
  hipMemsetAsync(HPp, 0, 2 * nbs * sizeof(float), stream);
  sincos_kernel<<<dim3(512), dim3(256), 0, stream>>>(POS, SS * DD);
  sincos_kernel<<<dim3(24), dim3(256), 0, stream>>>(TIM, NHOP * DD);
  embed_kernel<<<dim3(2048), dim3(256), 0, stream>>>(tokens, emb, TEN, (int)nbsd);
  asplit_kernel<<<dim3(2048), dim3(256), 0, stream>>>(enc, TINh, TINl, (int)nbsd);

  auto wsplit = [&](const float* W, _Float16* h, _Float16* l, int K, int N) {
    wsplit_kernel<<<dim3(N >> 5, K >> 5), dim3(256), 0, stream>>>(W, h, l, K, N);
  };
  wsplit(sa_qw, qkvWh, qkvWl, DD, DD);
  wsplit(sa_kw, qkvWh + wsm, qkvWl + wsm, DD, DD);
  wsplit(sa_vw, qkvWh + 2 * wsm, qkvWl + 2 * wsm, DD, DD);
  wsplit(sa_ow, saoWh, saoWl, DD, DD);
  wsplit(ca_qw, caqWh, caqWl, DD, DD);
  wsplit(ca_kw, FFHh, FFHh + wsm, DD, DD);              // temp in FFH
  wsplit(ca_vw, FFHh + 2 * wsm, FFHh + 3 * wsm, DD, DD);
  wsplit(ca_ow, caoWh, caoWl, DD, DD);
  wsplit(ff_w1, ff1Wh, ff1Wl, DD, FFD);
  wsplit(ff_w2, ff2Wh, ff2Wl, FFD, DD);
  concat3_kernel<<<dim3(12), dim3(256), 0, stream>>>(sa_qb, sa_kb, sa_vb, QKVB);

  auto gemmF = [&](const _Float16* ah, const _Float16* al, const _Float16* bh,
                   const _Float16* bl, const float* bi, float* cf, int M, int N,
                   int K) {
    gemm_pl<0><<<dim3(N / 64, M / 64), dim3(256), 0, stream>>>(
        ah, al, bh, bl, bi, cf, nullptr, nullptr, nullptr, nullptr, nullptr,
        nullptr, M, N, K, 1.f);
  };

  // hoisted: encoder K -> EK planes; encoder V -> EV transposed planes
  gemm_pl<3><<<dim3(16, 32), dim3(256), 0, stream>>>(
      TINh, TINl, FFHh, FFHh + wsm, ca_kb, nullptr, EKh, EKl, nullptr, nullptr,
      nullptr, nullptr, 2048, DD, DD, 1.f);
  gemm_pl<4><<<dim3(16, 32), dim3(256), 0, stream>>>(
      TINh, TINl, FFHh + 2 * wsm, FFHh + 3 * wsm, ca_vb, nullptr, EVh, EVl,
      nullptr, nullptr, nullptr, nullptr, 2048, DD, DD, 1.f);

  for (int t = 0; t < NHOP; ++t) {
    actcodes_kernel<<<dim3(2048), dim3(256), 0, stream>>>(
        TEN, POS, TIM, t, act_w, act_b, HPp, REMp, UWp, TINh, TINl);
    // fused QKV projection: 128x64 tile, grid (48,16)=768 (3/CU)
    gemm_big<2><<<dim3(48, 16), dim3(256), 0, stream>>>(
        TINh, TINl, qkvWh, qkvWl, QKVB, Qph, Qpl, Kph, Kpl, Vph, Vpl, 2048,
        3072, DD, 0.125f);
    flash_mfma<1><<<dim3(512), dim3(256), 0, stream>>>(
        Qph, Qpl, Kph, Kpl, Vph, Vpl, AOh, AOl, nullptr, SS);
    gemmF(AOh, AOl, saoWh, saoWl, sa_ob, PR, 2048, DD, DD);
    lnres_kernel<<<dim3(2048), dim3(256), 0, stream>>>(
        PR, TINh, TINl, ln1_g, ln1_b, nullptr, T2h, T2l, nullptr, nullptr, 1);
    gemm_pl<3><<<dim3(16, 32), dim3(256), 0, stream>>>(
        T2h, T2l, caqWh, caqWl, ca_qb, nullptr, CQh, CQl, nullptr, nullptr,
        nullptr, nullptr, 2048, DD, DD, 0.125f);
    flash_mfma<0><<<dim3(512), dim3(256), 0, stream>>>(
        CQh, CQl, EKh, EKl, EVh, EVl, AOh, AOl, encmask, SE);
    gemmF(AOh, AOl, caoWh, caoWl, ca_ob, PR, 2048, DD, DD);
    lnres_kernel<<<dim3(2048), dim3(256), 0, stream>>>(
        PR, T2h, T2l, ln2_g, ln2_b, nullptr, T3h, T3l, nullptr, nullptr, 1);
    // FFN: ff1 128x64 tile grid (64,16)=1024 (4/CU); ff2 64x64 grid 512
    gemm_big<1><<<dim3(64, 16), dim3(256), 0, stream>>>(
        T3h, T3l, ff1Wh, ff1Wl, ff_b1, FFHh, FFHl, nullptr, nullptr, nullptr,
        nullptr, 2048, FFD, DD, 1.f);
    gemmF(FFHh, FFHl, ff2Wh, ff2Wl, ff_b2, PR, 2048, DD, FFD);
    lnres_kernel<<<dim3(2048), dim3(256), 0, stream>>>(
        PR, T3h, T3l, ln3_g, ln3_b, TEN, nullptr, nullptr, UWp, out, 0);
  }
}